// Round 5
// baseline (978.588 us; speedup 1.0000x reference)
//
#include <hip/hip_runtime.h>
#include <math.h>

// BridgeNodes R5: single-pass bf16 MFMA GEMM (write-bound) + exact fixup of
// the threshold-discontinuity band.
//  - split_kernel: fp32 -> bf16 (RNE) into d_ws; also zeroes the fixup counter.
//  - bridge_mfma_kernel: 128x128 upper-tri tiles, mfma_f32_16x16x32_bf16,
//    full-K=128 LDS stage via global_load_lds(16B) with source-XOR swizzle
//    (keeps LDS dst lane-contiguous AND frag ds_read_b128 conflict-free).
//    Fast sigmoid (__expf + rcp). Entries with |dot - ln1.5| < 0.006 are
//    appended to a fixup list (bf16 dot error max ~1.7e-3 over 67M draws).
//  - fixup_kernel: recompute flagged entries with R1's exact sequential fp32
//    fmaf chain + precise expf (empirically matches np ref), write (r,c),(c,r).

constexpr int GROUPS = 4;
constexpr int N = 4096;
constexpr int F = 128;
constexpr int BT = 128;
constexpr int TILES = N / BT;                    // 32
constexpr int PAIRS = TILES * (TILES + 1) / 2;   // 528
constexpr float THRESH = 0.6f;
constexpr float LOGIT = 0.405465108f;            // ln(1.5)
constexpr float BAND = 0.006f;

// d_ws layout (bytes): [0,16) counter; [16, 16+8.39MB) bf16 levels; then list.
constexpr size_t H_OFF_SHORTS = 8;               // counter occupies 16 B
constexpr size_t H_ELEMS = (size_t)GROUPS * N * F;   // 2,097,152 shorts

using short8 = __attribute__((ext_vector_type(8))) short;
using f32x4  = __attribute__((ext_vector_type(4))) float;

__device__ __forceinline__ int row_start(int r) { return r * TILES - (r * (r - 1)) / 2; }

__device__ __forceinline__ short f2bf_rne(float x) {
    unsigned u = __float_as_uint(x);
    return (short)((u + 0x7FFFu + ((u >> 16) & 1u)) >> 16);
}

__global__ void split_kernel(const float* __restrict__ in, short* __restrict__ h,
                             unsigned* __restrict__ cnt) {
    const int i = blockIdx.x * 256 + threadIdx.x;
    if (i == 0) *cnt = 0;                        // zero fixup counter (ws is poisoned)
    if (i < (int)H_ELEMS) h[i] = f2bf_rne(in[i]);
}

#define GLL16(gp, lp)                                                        \
    __builtin_amdgcn_global_load_lds(                                        \
        (const __attribute__((address_space(1))) void*)(gp),                 \
        (__attribute__((address_space(3))) void*)(lp), 16, 0, 0)

__global__ __launch_bounds__(256, 2)
void bridge_mfma_kernel(const short* __restrict__ W, float* __restrict__ out,
                        unsigned* __restrict__ cnt, unsigned* __restrict__ list,
                        unsigned cap) {
    __shared__ alignas(16) short ldsA[BT * F];   // 32 KB
    __shared__ alignas(16) short ldsB[BT * F];   // 32 KB

    const int g = blockIdx.y;
    const int t = blockIdx.x;
    int bm = (int)((2 * TILES + 1
                    - sqrtf((float)((2 * TILES + 1) * (2 * TILES + 1) - 8 * t))) * 0.5f);
    bm = bm < 0 ? 0 : (bm > TILES - 1 ? TILES - 1 : bm);
    while (row_start(bm) > t) --bm;
    while (row_start(bm + 1) <= t) ++bm;
    const int bn = bm + (t - row_start(bm));

    const int tid  = threadIdx.x;
    const int lane = tid & 63;
    const int wv   = tid >> 6;
    const int lm   = lane & 15;
    const int q    = lane >> 4;
    const int R    = (wv & 1) * 64;
    const int C    = (wv >> 1) * 64;

    const short* baseA = W + ((size_t)g * N + bm * BT) * F;
    const short* baseB = W + ((size_t)g * N + bn * BT) * F;

    // ---- stage both tiles, full K=128, with source-side XOR octet swizzle ----
    // granule g0: row r = g0>>4, LDS octet slot o = g0&15 holds global octet
    // o^(r&15). Dst stays lane-contiguous (global_load_lds requirement).
#pragma unroll
    for (int it = 0; it < 8; ++it) {
        const int g0 = tid + 256 * it;
        const int r  = g0 >> 4;
        const int o  = g0 & 15;
        const int so = o ^ (r & 15);
        GLL16(baseA + (size_t)r * F + so * 8, &ldsA[g0 * 8]);
        GLL16(baseB + (size_t)r * F + so * 8, &ldsB[g0 * 8]);
    }
    __syncthreads();

    f32x4 acc[4][4] = {};
    // K-loop: 4 chunks of 32. frag octet oc = kc*4+q, stored at slot oc^(row&15).
#pragma unroll
    for (int kc = 0; kc < 4; ++kc) {
        short8 af[4], bf[4];
#pragma unroll
        for (int i = 0; i < 4; ++i) {
            const int row = R + i * 16 + lm;     // row & 15 == lm
            af[i] = *(const short8*)(ldsA + row * 16 * 8 + (((kc * 4 + q) ^ lm) * 8));
        }
#pragma unroll
        for (int j = 0; j < 4; ++j) {
            const int row = C + j * 16 + lm;
            bf[j] = *(const short8*)(ldsB + row * 16 * 8 + (((kc * 4 + q) ^ lm) * 8));
        }
#pragma unroll
        for (int i = 0; i < 4; ++i)
#pragma unroll
            for (int j = 0; j < 4; ++j)
                acc[i][j] = __builtin_amdgcn_mfma_f32_16x16x32_bf16(
                    af[i], bf[j], acc[i][j], 0, 0, 0);
    }

    // ---- epilogue: fast sigmoid + threshold + band flagging ----
    const size_t outg = (size_t)g * N * N;
    float val[4][4][4];
#pragma unroll
    for (int i = 0; i < 4; ++i)
#pragma unroll
        for (int j = 0; j < 4; ++j)
#pragma unroll
            for (int r = 0; r < 4; ++r) {
                const float x = acc[i][j][r];
                const float e = __expf(-x);
                const float s = __builtin_amdgcn_rcpf(1.0f + e);
                val[i][j][r] = (s < THRESH) ? 0.0f : s;
                if (fabsf(x - LOGIT) < BAND) {   // rare: ~0.05% of entries
                    const unsigned row = bm * BT + R + i * 16 + q * 4 + r;
                    const unsigned col = bn * BT + C + j * 16 + lm;
                    const unsigned idx = atomicAdd(cnt, 1u);
                    if (idx < cap)
                        list[idx] = ((unsigned)g << 24) | (row << 12) | col;
                }
            }

    // direct store: C/D layout col=lm, row=q*4+r
#pragma unroll
    for (int i = 0; i < 4; ++i)
#pragma unroll
        for (int r = 0; r < 4; ++r) {
            const int row = bm * BT + R + i * 16 + q * 4 + r;
            float* o = out + outg + (size_t)row * N + bn * BT + C;
#pragma unroll
            for (int j = 0; j < 4; ++j)
                o[j * 16 + lm] = val[i][j][r];
        }

    // mirror store (float4 per lane, full 64B lines across the 64 lanes)
    if (bm != bn) {
#pragma unroll
        for (int j = 0; j < 4; ++j) {
            const int mrow = bn * BT + C + j * 16 + lm;
            float* o = out + outg + (size_t)mrow * N + bm * BT + R;
#pragma unroll
            for (int i = 0; i < 4; ++i) {
                float4 v = {val[i][j][0], val[i][j][1], val[i][j][2], val[i][j][3]};
                *(float4*)(o + i * 16 + q * 4) = v;
            }
        }
    }
}

// ---- exact recompute of flagged entries: R1's fmaf chain + precise expf ----
__global__ void fixup_kernel(const float* __restrict__ nodes, float* __restrict__ out,
                             const unsigned* __restrict__ cnt,
                             const unsigned* __restrict__ list, unsigned cap) {
    unsigned n = *cnt;
    if (n > cap) n = cap;
    const unsigned stride = gridDim.x * blockDim.x;
    for (unsigned idx = blockIdx.x * blockDim.x + threadIdx.x; idx < n; idx += stride) {
        const unsigned p = list[idx];
        const unsigned g = p >> 24, row = (p >> 12) & 0xFFF, col = p & 0xFFF;
        const float* a = nodes + ((size_t)g * N + row) * F;
        const float* b = nodes + ((size_t)g * N + col) * F;
        float acc = 0.0f;
        for (int k = 0; k < F; ++k)              // sequential ascending-k: == R1 == np
            acc = fmaf(a[k], b[k], acc);
        const float s = 1.0f / (1.0f + expf(-acc));
        const float v = (s < THRESH) ? 0.0f : s;
        out[(size_t)g * N * N + (size_t)row * N + col] = v;
        out[(size_t)g * N * N + (size_t)col * N + row] = v;   // symmetric twin
    }
}

extern "C" void kernel_launch(void* const* d_in, const int* in_sizes, int n_in,
                              void* d_out, int out_size, void* d_ws, size_t ws_size,
                              hipStream_t stream) {
    const float* nodes = (const float*)d_in[0];
    float* out = (float*)d_out;

    unsigned* cnt = (unsigned*)d_ws;
    short* h = (short*)d_ws + H_OFF_SHORTS;                  // ws + 16 B
    const size_t list_off_bytes = 16 + H_ELEMS * sizeof(short);  // 16 + 4 MB... (2M shorts)
    unsigned* list = (unsigned*)((char*)d_ws + list_off_bytes);
    const size_t cap_sz = (ws_size > list_off_bytes + 16)
                              ? (ws_size - list_off_bytes) / sizeof(unsigned) : 0;
    const unsigned cap = (unsigned)(cap_sz > (1u << 22) ? (1u << 22) : cap_sz);

    split_kernel<<<(int)((H_ELEMS + 255) / 256), 256, 0, stream>>>(nodes, h, cnt);

    dim3 grid(PAIRS, GROUPS);                    // 528 x 4 = 2112 blocks
    bridge_mfma_kernel<<<grid, 256, 0, stream>>>(h, out, cnt, list, cap);

    fixup_kernel<<<512, 256, 0, stream>>>(nodes, out, cnt, list, cap);
}

// Round 6
// 332.585 us; speedup vs baseline: 2.9424x; 2.9424x over previous
//
#include <hip/hip_runtime.h>
#include <math.h>

// BridgeNodes R6: R5 (bf16 MFMA + threshold-band exact fixup) with the
// epilogue flag atomics aggregated per block (G12). R5's 728us main kernel
// was serialized on ~70k device-scope atomicAdds to ONE counter word; now:
// per-thread local collect -> LDS atomic per flagging thread -> ONE global
// atomic per block -> coalesced list writes.

constexpr int GROUPS = 4;
constexpr int N = 4096;
constexpr int F = 128;
constexpr int BT = 128;
constexpr int TILES = N / BT;                    // 32
constexpr int PAIRS = TILES * (TILES + 1) / 2;   // 528
constexpr float THRESH = 0.6f;
constexpr float LOGIT = 0.405465108f;            // ln(1.5)
constexpr float BAND = 0.006f;                   // >> max bf16 dot error (~1.7e-3)

constexpr size_t H_OFF_SHORTS = 8;               // counter occupies 16 B of ws
constexpr size_t H_ELEMS = (size_t)GROUPS * N * F;   // 2,097,152 bf16 elems

using short8 = __attribute__((ext_vector_type(8))) short;
using f32x4  = __attribute__((ext_vector_type(4))) float;

__device__ __forceinline__ int row_start(int r) { return r * TILES - (r * (r - 1)) / 2; }

__device__ __forceinline__ short f2bf_rne(float x) {
    unsigned u = __float_as_uint(x);
    return (short)((u + 0x7FFFu + ((u >> 16) & 1u)) >> 16);
}

__global__ void split_kernel(const float* __restrict__ in, short* __restrict__ h,
                             unsigned* __restrict__ cnt) {
    const int i = blockIdx.x * 256 + threadIdx.x;
    if (i == 0) *cnt = 0;                        // ws is re-poisoned each launch
    if (i < (int)H_ELEMS) h[i] = f2bf_rne(in[i]);
}

#define GLL16(gp, lp)                                                        \
    __builtin_amdgcn_global_load_lds(                                        \
        (const __attribute__((address_space(1))) void*)(gp),                 \
        (__attribute__((address_space(3))) void*)(lp), 16, 0, 0)

__global__ __launch_bounds__(256, 2)
void bridge_mfma_kernel(const short* __restrict__ W, float* __restrict__ out,
                        unsigned* __restrict__ cnt, unsigned* __restrict__ list,
                        unsigned cap) {
    __shared__ alignas(16) short ldsA[BT * F];   // 32 KB
    __shared__ alignas(16) short ldsB[BT * F];   // 32 KB

    const int g = blockIdx.y;
    const int t = blockIdx.x;
    int bm = (int)((2 * TILES + 1
                    - sqrtf((float)((2 * TILES + 1) * (2 * TILES + 1) - 8 * t))) * 0.5f);
    bm = bm < 0 ? 0 : (bm > TILES - 1 ? TILES - 1 : bm);
    while (row_start(bm) > t) --bm;
    while (row_start(bm + 1) <= t) ++bm;
    const int bn = bm + (t - row_start(bm));

    const int tid  = threadIdx.x;
    const int lane = tid & 63;
    const int wv   = tid >> 6;
    const int lm   = lane & 15;
    const int q    = lane >> 4;
    const int R    = (wv & 1) * 64;
    const int C    = (wv >> 1) * 64;

    const short* baseA = W + ((size_t)g * N + bm * BT) * F;
    const short* baseB = W + ((size_t)g * N + bn * BT) * F;

    // ---- stage both tiles, full K=128, source-side XOR octet swizzle ----
    // (R5-proven: SQ_LDS_BANK_CONFLICT == 0)
#pragma unroll
    for (int it = 0; it < 8; ++it) {
        const int g0 = tid + 256 * it;
        const int r  = g0 >> 4;
        const int o  = g0 & 15;
        const int so = o ^ (r & 15);
        GLL16(baseA + (size_t)r * F + so * 8, &ldsA[g0 * 8]);
        GLL16(baseB + (size_t)r * F + so * 8, &ldsB[g0 * 8]);
    }
    __syncthreads();

    f32x4 acc[4][4] = {};
#pragma unroll
    for (int kc = 0; kc < 4; ++kc) {
        short8 af[4], bf[4];
#pragma unroll
        for (int i = 0; i < 4; ++i) {
            const int row = R + i * 16 + lm;
            af[i] = *(const short8*)(ldsA + row * 16 * 8 + (((kc * 4 + q) ^ lm) * 8));
        }
#pragma unroll
        for (int j = 0; j < 4; ++j) {
            const int row = C + j * 16 + lm;
            bf[j] = *(const short8*)(ldsB + row * 16 * 8 + (((kc * 4 + q) ^ lm) * 8));
        }
#pragma unroll
        for (int i = 0; i < 4; ++i)
#pragma unroll
            for (int j = 0; j < 4; ++j)
                acc[i][j] = __builtin_amdgcn_mfma_f32_16x16x32_bf16(
                    af[i], bf[j], acc[i][j], 0, 0, 0);
    }

    // all waves done reading frags -> ldsA reusable as block counters
    __syncthreads();
    unsigned* sc = (unsigned*)ldsA;              // sc[0]=blkCnt, sc[1]=blkBase
    if (tid == 0) sc[0] = 0;

    // ---- epilogue: fast sigmoid + threshold; collect band flags locally ----
    float val[4][4][4];
    unsigned local[8];
    int nf = 0;
#pragma unroll
    for (int i = 0; i < 4; ++i)
#pragma unroll
        for (int j = 0; j < 4; ++j)
#pragma unroll
            for (int r = 0; r < 4; ++r) {
                const float x = acc[i][j][r];
                const float e = __expf(-x);
                const float s = __builtin_amdgcn_rcpf(1.0f + e);
                val[i][j][r] = (s < THRESH) ? 0.0f : s;
                if (fabsf(x - LOGIT) < BAND) {   // ~0.2% of threads per entry
                    const unsigned row = bm * BT + R + i * 16 + q * 4 + r;
                    const unsigned col = bn * BT + C + j * 16 + lm;
                    const unsigned enc = ((unsigned)g << 24) | (row << 12) | col;
                    if (nf < 8) local[nf++] = enc;
                    else {                       // statistically never (P ~ 1e-13)
                        const unsigned idx = atomicAdd(cnt, 1u);
                        if (idx < cap) list[idx] = enc;
                    }
                }
            }

    const size_t outg = (size_t)g * N * N;

    // direct store: C/D layout col=lm, row=q*4+r (4 full 64B lines per wave-inst)
#pragma unroll
    for (int i = 0; i < 4; ++i)
#pragma unroll
        for (int r = 0; r < 4; ++r) {
            const int row = bm * BT + R + i * 16 + q * 4 + r;
            float* o = out + outg + (size_t)row * N + bn * BT + C;
#pragma unroll
            for (int j = 0; j < 4; ++j)
                o[j * 16 + lm] = val[i][j][r];
        }

    // mirror store (float4 per lane, full 64B lines across the wave)
    if (bm != bn) {
#pragma unroll
        for (int j = 0; j < 4; ++j) {
            const int mrow = bn * BT + C + j * 16 + lm;
            float* o = out + outg + (size_t)mrow * N + bm * BT + R;
#pragma unroll
            for (int i = 0; i < 4; ++i) {
                float4 v = {val[i][j][0], val[i][j][1], val[i][j][2], val[i][j][3]};
                *(float4*)(o + i * 16 + q * 4) = v;
            }
        }
    }

    // ---- block-aggregated flag publication: ONE global atomic per block ----
    __syncthreads();                             // sc[0] zeroed & visible
    unsigned myoff = 0;
    if (nf) myoff = atomicAdd(&sc[0], (unsigned)nf);   // LDS atomic, rare takers
    __syncthreads();
    if (tid == 0) sc[1] = sc[0] ? atomicAdd(cnt, sc[0]) : 0u;
    __syncthreads();
    if (nf) {
        const unsigned base = sc[1] + myoff;
        for (int k = 0; k < nf; ++k)
            if (base + k < cap) list[base + k] = local[k];
    }
}

// ---- exact recompute of flagged entries: R1's fmaf chain + precise expf ----
__global__ void fixup_kernel(const float* __restrict__ nodes, float* __restrict__ out,
                             const unsigned* __restrict__ cnt,
                             const unsigned* __restrict__ list, unsigned cap) {
    unsigned n = *cnt;
    if (n > cap) n = cap;
    const unsigned stride = gridDim.x * blockDim.x;
    for (unsigned idx = blockIdx.x * blockDim.x + threadIdx.x; idx < n; idx += stride) {
        const unsigned p = list[idx];
        const unsigned g = p >> 24, row = (p >> 12) & 0xFFF, col = p & 0xFFF;
        const float* a = nodes + ((size_t)g * N + row) * F;
        const float* b = nodes + ((size_t)g * N + col) * F;
        float acc = 0.0f;
        for (int k = 0; k < F; ++k)              // sequential ascending-k == np
            acc = fmaf(a[k], b[k], acc);
        const float s = 1.0f / (1.0f + expf(-acc));
        const float v = (s < THRESH) ? 0.0f : s;
        out[(size_t)g * N * N + (size_t)row * N + col] = v;
        out[(size_t)g * N * N + (size_t)col * N + row] = v;
    }
}

extern "C" void kernel_launch(void* const* d_in, const int* in_sizes, int n_in,
                              void* d_out, int out_size, void* d_ws, size_t ws_size,
                              hipStream_t stream) {
    const float* nodes = (const float*)d_in[0];
    float* out = (float*)d_out;

    unsigned* cnt = (unsigned*)d_ws;
    short* h = (short*)d_ws + H_OFF_SHORTS;
    const size_t list_off_bytes = 16 + H_ELEMS * sizeof(short);
    unsigned* list = (unsigned*)((char*)d_ws + list_off_bytes);
    const size_t cap_sz = (ws_size > list_off_bytes + 16)
                              ? (ws_size - list_off_bytes) / sizeof(unsigned) : 0;
    const unsigned cap = (unsigned)(cap_sz > (1u << 22) ? (1u << 22) : cap_sz);

    split_kernel<<<(int)((H_ELEMS + 255) / 256), 256, 0, stream>>>(nodes, h, cnt);

    dim3 grid(PAIRS, GROUPS);
    bridge_mfma_kernel<<<grid, 256, 0, stream>>>(h, out, cnt, list, cap);

    fixup_kernel<<<512, 256, 0, stream>>>(nodes, out, cnt, list, cap);
}